// Round 2
// baseline (155.765 us; speedup 1.0000x reference)
//
#include <hip/hip_runtime.h>

// Involution2d: B=8, C=256, G=4 (Cpg=64), H=W=Ho=Wo=64, K=7, PAD=3, STRIDE=1.
// out[b, g*64+c, y, x] = sum_{kh,kw} in[b, g*64+c, y+kh-3, x+kw-3] * w[b,g,kh,kw,y,x] + bias[g*64+c]
//
// R2 structure: channel-accumulator blocking. Each thread owns 4 x-pixels x
// NC=8 channels of accumulators (32 VGPRs). Weights STREAM (each tap's float4
// loaded once, used across 8 channels, then dead) -- fixes R1's L2-bound
// weight re-fetch (VGPR=128 proved the 196-reg weight array was spilled;
// 1.6 GB L2 traffic ~= the whole 48 us). Input: 8 channels x 22x72 tile
// staged in LDS ONCE per block (single barrier), register sliding window
// in x per kh row via aligned ds_read_b128/b64 (stride 72 keeps 16B align).

#define BLK_X 16
#define BLK_Y 16
#define NTHR (BLK_X * BLK_Y)   // 256
#define NC 8                   // channels per block
#define TILE_Y 16
#define STG_ROWS (TILE_Y + 6)  // 22
#define STG_COLS 70            // 64 + 6 halo
#define LDS_STRIDE 72          // even: keeps b128/b64 alignment; 72%32=8 spreads rows
#define STG_N (NC * STG_ROWS * STG_COLS)   // 12320

__global__ __launch_bounds__(NTHR, 3)   // cap ~170 VGPR: forbids hoisting all 49 w-loads
void involution_kernel(const float* __restrict__ in,
                       const float* __restrict__ w,
                       const float* __restrict__ bias,
                       float* __restrict__ out) {
    __shared__ float lds[NC * STG_ROWS * LDS_STRIDE];  // 50688 B -> 3 blocks/CU

    const int tx = threadIdx.x;       // 0..15  (x-quad)
    const int ty = threadIdx.y;       // 0..15  (row)
    const int tid = ty * BLK_X + tx;
    const int x0 = tx * 4;
    const int Y0 = blockIdx.x * TILE_Y;
    const int y  = Y0 + ty;
    const int c0 = blockIdx.y * NC;   // channel-in-group base
    const int bz = blockIdx.z;        // b*4 + g
    const int g  = bz & 3;

    const float* inb = in + (size_t)bz * 64 * 4096 + (size_t)c0 * 4096;

    // ---- stage NC channels of the haloed input tile into LDS (once) ----
    #pragma unroll
    for (int j = 0; j < (STG_N + NTHR - 1) / NTHR; ++j) {
        int i = tid + j * NTHR;
        if (i < STG_N) {
            int ci  = i / (STG_ROWS * STG_COLS);
            int rem = i - ci * (STG_ROWS * STG_COLS);
            int rr  = rem / STG_COLS;
            int cc  = rem - rr * STG_COLS;
            int gy  = Y0 + rr - 3;
            int gx  = cc - 3;
            float v = 0.f;
            if (gy >= 0 && gy < 64 && gx >= 0 && gx < 64)
                v = inb[ci * 4096 + gy * 64 + gx];
            lds[(ci * STG_ROWS + rr) * LDS_STRIDE + cc] = v;
        }
    }
    __syncthreads();

    float acc[NC][4];
    #pragma unroll
    for (int ci = 0; ci < NC; ++ci) {
        acc[ci][0] = 0.f; acc[ci][1] = 0.f; acc[ci][2] = 0.f; acc[ci][3] = 0.f;
    }

    const float* wb = w + (size_t)bz * 49 * 4096 + y * 64 + x0;

    #pragma unroll
    for (int kh = 0; kh < 7; ++kh) {
        // register window: 10 floats per channel for this kh row
        float vals[NC][10];
        #pragma unroll
        for (int ci = 0; ci < NC; ++ci) {
            const float* lr = &lds[(ci * STG_ROWS + ty + kh) * LDS_STRIDE + x0];
            float4 a = *(const float4*)lr;         // 16B aligned
            float4 b = *(const float4*)(lr + 4);
            float2 c = *(const float2*)(lr + 8);
            vals[ci][0] = a.x; vals[ci][1] = a.y; vals[ci][2] = a.z; vals[ci][3] = a.w;
            vals[ci][4] = b.x; vals[ci][5] = b.y; vals[ci][6] = b.z; vals[ci][7] = b.w;
            vals[ci][8] = c.x; vals[ci][9] = c.y;
        }
        #pragma unroll
        for (int kw = 0; kw < 7; ++kw) {
            const float4 wv = *(const float4*)(wb + (size_t)(kh * 7 + kw) * 4096);
            #pragma unroll
            for (int ci = 0; ci < NC; ++ci) {
                acc[ci][0] += vals[ci][kw + 0] * wv.x;
                acc[ci][1] += vals[ci][kw + 1] * wv.y;
                acc[ci][2] += vals[ci][kw + 2] * wv.z;
                acc[ci][3] += vals[ci][kw + 3] * wv.w;
            }
        }
    }

    // ---- epilogue: bias + coalesced float4 stores ----
    float* outb = out + (size_t)bz * 64 * 4096 + (size_t)c0 * 4096 + y * 64 + x0;
    #pragma unroll
    for (int ci = 0; ci < NC; ++ci) {
        const float bv = bias[g * 64 + c0 + ci];
        float4 o;
        o.x = acc[ci][0] + bv; o.y = acc[ci][1] + bv;
        o.z = acc[ci][2] + bv; o.w = acc[ci][3] + bv;
        *(float4*)(outb + (size_t)ci * 4096) = o;
    }
}

extern "C" void kernel_launch(void* const* d_in, const int* in_sizes, int n_in,
                              void* d_out, int out_size, void* d_ws, size_t ws_size,
                              hipStream_t stream) {
    const float* in   = (const float*)d_in[0];  // (8,256,64,64)
    const float* wgt  = (const float*)d_in[1];  // (8,4,7,7,64,64)
    const float* bias = (const float*)d_in[2];  // (256,)
    float* out = (float*)d_out;                 // (8,256,64,64)

    dim3 block(BLK_X, BLK_Y, 1);                  // 256 threads
    dim3 grid(64 / TILE_Y, 64 / NC, 32);          // (4, 8, 32) = 1024 blocks
    involution_kernel<<<grid, block, 0, stream>>>(in, wgt, bias, out);
}